// Round 3
// baseline (1643.786 us; speedup 1.0000x reference)
//
#include <hip/hip_runtime.h>
#include <hip/hip_bf16.h>

// Problem: B=2, S=2048, D=1024, H=16, DH=64.
// Inputs (fp32 per reference): x [2,2048,1024], mask int32 [2,2048,2048],
//   w*_w [1024,1024], w*_b [1024].
// d_out (fp32): out (2*2048*1024) ++ attn (2*16*2048*2048), flat.
// d_ws: q (8MB) | k (8MB) | Vt (8MB) bf16; ctx reuses q slot. Needs 24 MB.

typedef __bf16 bf16_t;
typedef __bf16 bf16x8 __attribute__((ext_vector_type(8)));
typedef float f32x4 __attribute__((ext_vector_type(4)));
typedef float f32x8 __attribute__((ext_vector_type(8)));

#define MFMA16(a, b, c) __builtin_amdgcn_mfma_f32_16x16x32_bf16((a), (b), (c), 0, 0, 0)

// Verified gfx950 16x16x32 bf16 layouts (learn_hip m89/m91):
//   A-frag a[j] = A[m][k], m = lane&15, k = (lane>>4)*8 + j
//   B-frag b[j] = B[k][n], n = lane&15, k = (lane>>4)*8 + j
//   D-frag d[r] = D[row][col], col = lane&15, row = (lane>>4)*4 + r

__device__ inline bf16x8 loadfrag(const float* p) {
  f32x8 f = *(const f32x8*)p;
  bf16x8 o;
#pragma unroll
  for (int j = 0; j < 8; ++j) o[j] = (bf16_t)f[j];
  return o;
}
__device__ inline bf16x8 loadfrag(const bf16_t* p) { return *(const bf16x8*)p; }

// ---------------------------------------------------------------------------
// Projection GEMM: C[4096,1024] = A[4096,1024] * W[1024,1024]^T + bias
// A: fp32 (x) or bf16 (ctx). C: bf16 (ws) or fp32 (final out).
// MODE 0: row-major store. MODE 1: store V transposed per head:
//         Vt[((b*16+h)*64 + d)*2048 + s]
// Per wave: one 16x64 output stripe (4 n-tiles), K-step 32.
// ---------------------------------------------------------------------------
template <int MODE, typename TA, typename TC>
__global__ void gemm_bias_k(const TA* __restrict__ A,
                            const float* __restrict__ W,
                            const float* __restrict__ bias,
                            TC* __restrict__ C) {
  const int N = 1024, K = 1024;
  int wave = (blockIdx.x * blockDim.x + threadIdx.x) >> 6;  // 0..4095
  int lane = threadIdx.x & 63;
  int quad = lane >> 4, r = lane & 15;
  int tm = wave >> 4;   // 0..255
  int tn = wave & 15;   // 0..15
  int m0 = tm * 16, n0 = tn * 64;

  const TA* arow = A + (size_t)(m0 + r) * K + quad * 8;
  const float* wbase = W + (size_t)(n0 + r) * K + quad * 8;

  f32x4 acc[4] = {};
  for (int k0 = 0; k0 < K; k0 += 32) {
    bf16x8 af = loadfrag(arow + k0);
#pragma unroll
    for (int t = 0; t < 4; ++t) {
      bf16x8 bfr = loadfrag(wbase + (size_t)t * 16 * K + k0);
      acc[t] = MFMA16(af, bfr, acc[t]);
    }
  }
#pragma unroll
  for (int t = 0; t < 4; ++t) {
#pragma unroll
    for (int i = 0; i < 4; ++i) {
      int row = m0 + quad * 4 + i;
      int col = n0 + t * 16 + r;
      float v = acc[t][i] + bias[col];
      if (MODE == 0) {
        C[(size_t)row * N + col] = (TC)v;
      } else {
        int b = row >> 11, s = row & 2047;
        int h = col >> 6, d = col & 63;
        C[((size_t)(b * 16 + h) * 64 + d) * 2048 + s] = (TC)v;
      }
    }
  }
}

// ---------------------------------------------------------------------------
// scores = scale * Q K^T (+ mask) -> raw (pre-softmax) fp32 into attn region.
// Per (b,h): M=2048, N=2048, Kdim=64. Per wave: 16x64 stripe.
// ---------------------------------------------------------------------------
__global__ void scores_k(const bf16_t* __restrict__ Q, const bf16_t* __restrict__ Km,
                         const int* __restrict__ mask, float* __restrict__ attn) {
  int wave = (blockIdx.x * blockDim.x + threadIdx.x) >> 6;  // 0..131071
  int lane = threadIdx.x & 63;
  int quad = lane >> 4, r = lane & 15;
  int bh = wave >> 12;
  int t = wave & 4095;
  int tm = t >> 5, tn = t & 31;
  int b = bh >> 4, h = bh & 15;
  int m0 = tm * 16, n0 = tn * 64;

  const bf16_t* qrow = Q + (size_t)(b * 2048 + m0 + r) * 1024 + h * 64 + quad * 8;
  const bf16_t* krow = Km + (size_t)(b * 2048 + n0 + r) * 1024 + h * 64 + quad * 8;

  f32x4 acc[4] = {};
#pragma unroll
  for (int k0 = 0; k0 < 64; k0 += 32) {
    bf16x8 af = *(const bf16x8*)(qrow + k0);
#pragma unroll
    for (int tt = 0; tt < 4; ++tt) {
      bf16x8 bfr = *(const bf16x8*)(krow + (size_t)tt * 16 * 1024 + k0);
      acc[tt] = MFMA16(af, bfr, acc[tt]);
    }
  }

  float* arow = attn + (size_t)bh * 2048 * 2048;
  const int* mrow = mask + (size_t)b * 2048 * 2048;
#pragma unroll
  for (int tt = 0; tt < 4; ++tt) {
#pragma unroll
    for (int i = 0; i < 4; ++i) {
      int row = m0 + quad * 4 + i;
      int col = n0 + tt * 16 + r;
      float s = acc[tt][i] * 0.125f;  // DH^-0.5
      if (mrow[(size_t)row * 2048 + col] == 0) s = -1e9f;
      arow[(size_t)row * 2048 + col] = s;
    }
  }
}

// ---------------------------------------------------------------------------
// In-place fp32 row softmax over attn: one block (256 thr) per row of 2048.
// ---------------------------------------------------------------------------
__global__ void softmax_k(float* __restrict__ attn) {
  size_t row = blockIdx.x;  // 0..65535
  float* p = attn + row * 2048 + threadIdx.x * 8;
  f32x8 v = *(const f32x8*)p;
  float f[8];
#pragma unroll
  for (int j = 0; j < 8; ++j) f[j] = v[j];

  float m = f[0];
#pragma unroll
  for (int j = 1; j < 8; ++j) m = fmaxf(m, f[j]);
#pragma unroll
  for (int off = 32; off; off >>= 1) m = fmaxf(m, __shfl_xor(m, off));

  __shared__ float red[8];
  int wid = threadIdx.x >> 6, lane = threadIdx.x & 63;
  if (lane == 0) red[wid] = m;
  __syncthreads();
  m = fmaxf(fmaxf(red[0], red[1]), fmaxf(red[2], red[3]));

  float sum = 0.f;
#pragma unroll
  for (int j = 0; j < 8; ++j) {
    f[j] = __expf(f[j] - m);
    sum += f[j];
  }
#pragma unroll
  for (int off = 32; off; off >>= 1) sum += __shfl_xor(sum, off);
  if (lane == 0) red[4 + wid] = sum;
  __syncthreads();
  sum = red[4] + red[5] + red[6] + red[7];
  float inv = 1.f / sum;

  f32x8 o;
#pragma unroll
  for (int j = 0; j < 8; ++j) o[j] = f[j] * inv;
  *(f32x8*)p = o;
}

// ---------------------------------------------------------------------------
// ctx = P * V. Per (b,h): M=2048, N=64, Kdim=2048. Per wave: 16x64 stripe.
// attn fp32 (converted inline); V pre-transposed bf16: Vt[bh][d][s].
// ctx row-major [b*2048+q][h*64+d], bf16.
// ---------------------------------------------------------------------------
__global__ void pv_k(const float* __restrict__ attn, const bf16_t* __restrict__ Vt,
                     bf16_t* __restrict__ ctx) {
  int wave = (blockIdx.x * blockDim.x + threadIdx.x) >> 6;  // 0..4095
  int lane = threadIdx.x & 63;
  int quad = lane >> 4, r = lane & 15;
  int bh = wave >> 7;     // 0..31
  int tm = wave & 127;    // 0..127
  int b = bh >> 4, h = bh & 15;
  int m0 = tm * 16;

  const float* prow = attn + ((size_t)bh * 2048 + m0 + r) * 2048 + quad * 8;
  const bf16_t* vrow = Vt + ((size_t)bh * 64 + r) * 2048 + quad * 8;

  f32x4 acc[4] = {};
  for (int k0 = 0; k0 < 2048; k0 += 32) {
    bf16x8 af = loadfrag(prow + k0);
#pragma unroll
    for (int tt = 0; tt < 4; ++tt) {
      bf16x8 bfr = *(const bf16x8*)(vrow + (size_t)tt * 16 * 2048 + k0);
      acc[tt] = MFMA16(af, bfr, acc[tt]);
    }
  }
#pragma unroll
  for (int tt = 0; tt < 4; ++tt) {
#pragma unroll
    for (int i = 0; i < 4; ++i) {
      int row = m0 + quad * 4 + i;
      int col = tt * 16 + r;
      ctx[((size_t)b * 2048 + row) * 1024 + h * 64 + col] = (bf16_t)acc[tt][i];
    }
  }
}

extern "C" void kernel_launch(void* const* d_in, const int* in_sizes, int n_in,
                              void* d_out, int out_size, void* d_ws, size_t ws_size,
                              hipStream_t stream) {
  const float* x    = (const float*)d_in[0];
  const int*   mask = (const int*)d_in[1];
  const float* wq_w = (const float*)d_in[2];
  const float* wq_b = (const float*)d_in[3];
  const float* wk_w = (const float*)d_in[4];
  const float* wk_b = (const float*)d_in[5];
  const float* wv_w = (const float*)d_in[6];
  const float* wv_b = (const float*)d_in[7];
  const float* wo_w = (const float*)d_in[8];
  const float* wo_b = (const float*)d_in[9];

  float* out  = (float*)d_out;
  float* attn = out + (size_t)2 * 2048 * 1024;

  const size_t MB8 = (size_t)4096 * 1024;  // elements per 4096x1024 bf16 buffer
  bf16_t* qbuf = (bf16_t*)d_ws;
  bf16_t* kbuf = qbuf + MB8;
  bf16_t* vtb  = qbuf + 2 * MB8;
  bf16_t* ctx  = qbuf;  // reuse q slot after scores_k

  dim3 blk(256);
  gemm_bias_k<0, float, bf16_t><<<1024, blk, 0, stream>>>(x, wq_w, wq_b, qbuf);
  gemm_bias_k<0, float, bf16_t><<<1024, blk, 0, stream>>>(x, wk_w, wk_b, kbuf);
  gemm_bias_k<1, float, bf16_t><<<1024, blk, 0, stream>>>(x, wv_w, wv_b, vtb);
  scores_k<<<32768, blk, 0, stream>>>(qbuf, kbuf, mask, attn);
  softmax_k<<<65536, blk, 0, stream>>>(attn);
  pv_k<<<1024, blk, 0, stream>>>(attn, vtb, ctx);
  gemm_bias_k<0, bf16_t, float><<<1024, blk, 0, stream>>>(ctx, wo_w, wo_b, out);
}